// Round 3
// baseline (601.566 us; speedup 1.0000x reference)
//
#include <hip/hip_runtime.h>
#include <hip/hip_bf16.h>

typedef float f2  __attribute__((ext_vector_type(2)));
typedef float f4v __attribute__((ext_vector_type(4)));

#ifndef __has_builtin
#define __has_builtin(x) 0
#endif

#define HID   32
#define TLEN  2048
#define BATCH 512
#define L2E   1.4426950408889634f   /* log2(e) */

__device__ __forceinline__ float fast_rcp(float x) {
#if __has_builtin(__builtin_amdgcn_rcpf)
    return __builtin_amdgcn_rcpf(x);
#else
    return 1.0f / x;
#endif
}
__device__ __forceinline__ float fast_rsq(float x) {
#if __has_builtin(__builtin_amdgcn_rsqf)
    return __builtin_amdgcn_rsqf(x);
#else
    return rsqrtf(x);
#endif
}
__device__ __forceinline__ float fast_exp2(float x) {
#if __has_builtin(__builtin_amdgcn_exp2f)
    return __builtin_amdgcn_exp2f(x);
#else
    return exp2f(x);
#endif
}

// sum of x over lane pairs (l, l^32) WITHOUT touching the DS pipe.
// v_permlane32_swap_b32 exchanges lanes0-31 of D with lanes32-63 of S;
// with both inputs = x, newD + newS == x[lane] + x[lane^32] in every lane.
__device__ __forceinline__ float xor32_sum(float x) {
#if __has_builtin(__builtin_amdgcn_permlane32_swap)
    typedef unsigned int u2v __attribute__((ext_vector_type(2)));
    u2v r = __builtin_amdgcn_permlane32_swap(__float_as_uint(x), __float_as_uint(x),
                                             false, false);
    return __uint_as_float(r.x) + __uint_as_float(r.y);
#else
    float a = x, b = x;
    asm("v_permlane32_swap_b32 %0, %1" : "+&v"(a), "+&v"(b));
    return a + b;
#endif
}

// ds_swizzle xor within 32-lane groups (BitMode: offset=(xor<<10)|(or<<5)|and)
#if __has_builtin(__builtin_amdgcn_ds_swizzle)
#define SWZ_XOR(x, XORM) \
    __int_as_float(__builtin_amdgcn_ds_swizzle(__float_as_int(x), ((XORM) << 10) | 0x1F))
#else
#define SWZ_XOR(x, XORM) __shfl_xor((x), (XORM))
#endif

// compile-time-index extraction from an f4v array (keeps values in registers)
#define ELT(arr, i) ((i) % 4 == 0 ? (arr)[(i)/4].x : \
                     (i) % 4 == 1 ? (arr)[(i)/4].y : \
                     (i) % 4 == 2 ? (arr)[(i)/4].z : (arr)[(i)/4].w)

// One wave per block, one batch element per wave.
// Gates: lane l -> output j = l&31, K-half = l>>5 (16-wide partial dot);
//        halves combined with permlane32_swap (VALU, no DS latency on chain).
// q-head: batched every 8 steps from an 8-slot h history ring in LDS:
//        lane l -> timestep tq = l>>3, K-half kq = (l>>2)&1, output m = l&3.
// All weights pre-scaled by log2e (r,z) / 2*log2e (n) so sigmoid/tanh use
// raw v_exp_f32 (=exp2) with no input multiply.
__global__ __launch_bounds__(64) void gru_fused_kernel(
    const float* __restrict__ acc_g, const float* __restrict__ mag_g,
    const float* __restrict__ W_ih, const float* __restrict__ W_hh,
    const float* __restrict__ b_ih, const float* __restrict__ b_hh,
    const float* __restrict__ Wq, const float* __restrict__ bq,
    float* __restrict__ out)
{
    const int lane = threadIdx.x;
    const int j    = lane & 31;
    const int half = lane >> 5;
    const int kb   = half * 16;
    const int b    = blockIdx.x;

    const int tq = lane >> 3;        // q-head: timestep within 8-window
    const int kq = (lane >> 2) & 1;  // q-head: K-half
    const int m  = lane & 3;         // q-head: output component

    __shared__ float hbuf[8 * HID];  // h history ring, slot s = h after step (t0+s)

    // ---- per-lane weight preload (registers), with exp2 pre-scaling ----
    f2 wr[8], wz[8], wn[8];
#pragma unroll
    for (int p = 0; p < 8; ++p) {
        wr[p] = L2E          * *reinterpret_cast<const f2*>(W_hh + (0 * HID + j) * HID + kb + 2 * p);
        wz[p] = L2E          * *reinterpret_cast<const f2*>(W_hh + (1 * HID + j) * HID + kb + 2 * p);
        wn[p] = (2.0f * L2E) * *reinterpret_cast<const f2*>(W_hh + (2 * HID + j) * HID + kb + 2 * p);
    }
    f4v wq4[4];
#pragma unroll
    for (int i = 0; i < 4; ++i)
        wq4[i] = *reinterpret_cast<const f4v*>(Wq + m * HID + kq * 16 + 4 * i);

    // gi weights: r/z HALVED (both K-halves accumulate (W/2)x pre-combine, the
    // permlane sum restores W*x); n-gate gi stays full (added post-combine,
    // since r multiplies only the hh part).
    float wir[6], wiz[6], win[6];
#pragma unroll
    for (int i = 0; i < 6; ++i) {
        wir[i] = 0.5f * L2E * W_ih[(0 * HID + j) * 6 + i];
        wiz[i] = 0.5f * L2E * W_ih[(1 * HID + j) * 6 + i];
        win[i] = 2.0f * L2E * W_ih[(2 * HID + j) * 6 + i];
    }
    const float br_s  = 0.5f * L2E * (b_ih[0 * HID + j] + b_hh[0 * HID + j]); // halved, pre-combine
    const float bz_s  = 0.5f * L2E * (b_ih[1 * HID + j] + b_hh[1 * HID + j]);
    const float bhn_s = L2E * b_hh[2 * HID + j];          // = 0.5 * 2L * bhn, pre-combine
    const float bin_s = 2.0f * L2E * b_ih[2 * HID + j];   // full, post-combine
    const float bqv   = bq[m];

    hbuf[7 * HID + j] = 0.0f;        // h_{-1} = 0 (slot 7; dup write from halves is benign)

    const float* accp = acc_g + (size_t)b * TLEN * 3;
    const float* magp = mag_g + (size_t)b * TLEN * 3;
    float* outp = out + (size_t)b * TLEN * 4;

    float h = 0.0f;                  // this lane's h_j

    // ---- one GRU step: read h_{t-1} from slot sp, write h_t to slot ss ----
    auto step = [&](int sp, int ss, float a0, float a1, float a2,
                                    float m0, float m1, float m2) {
        const float* hb = &hbuf[sp * HID + kb];
        f4v A = *reinterpret_cast<const f4v*>(hb + 0);   // broadcast ds_read_b128 x4
        f4v B = *reinterpret_cast<const f4v*>(hb + 4);
        f4v C = *reinterpret_cast<const f4v*>(hb + 8);
        f4v D = *reinterpret_cast<const f4v*>(hb + 12);
        f2 hp[8] = { {A.x,A.y},{A.z,A.w},{B.x,B.y},{B.z,B.w},
                     {C.x,C.y},{C.z,C.w},{D.x,D.y},{D.z,D.w} };

        // 16-wide partial dots, 2 accumulators per gate (4-deep chains)
        f2 dr0 = wr[0] * hp[0]; f2 dr1 = wr[4] * hp[4];
        f2 dz0 = wz[0] * hp[0]; f2 dz1 = wz[4] * hp[4];
        f2 dn0 = wn[0] * hp[0]; f2 dn1 = wn[4] * hp[4];
#pragma unroll
        for (int p = 1; p < 4; ++p) {
            dr0 += wr[p] * hp[p];  dr1 += wr[p + 4] * hp[p + 4];
            dz0 += wz[p] * hp[p];  dz1 += wz[p + 4] * hp[p + 4];
            dn0 += wn[p] * hp[p];  dn1 += wn[p + 4] * hp[p + 4];
        }

        // input-gate chains (independent of h -> fills LDS-read latency)
        float gr = fmaf(a2, wir[2], fmaf(a1, wir[1], fmaf(a0, wir[0], br_s)));
        gr = fmaf(m2, wir[5], fmaf(m1, wir[4], fmaf(m0, wir[3], gr)));
        float gz = fmaf(a2, wiz[2], fmaf(a1, wiz[1], fmaf(a0, wiz[0], bz_s)));
        gz = fmaf(m2, wiz[5], fmaf(m1, wiz[4], fmaf(m0, wiz[3], gz)));
        float gn = fmaf(a2, win[2], fmaf(a1, win[1], fmaf(a0, win[0], bin_s)));
        gn = fmaf(m2, win[5], fmaf(m1, win[4], fmaf(m0, win[3], gn)));

        // horizontal + cross-half combine (permlane32_swap: VALU, not DS)
        f2 drs = dr0 + dr1; float sr = drs.x + drs.y + gr;
        f2 dzs = dz0 + dz1; float sz = dzs.x + dzs.y + gz;
        f2 dns = dn0 + dn1; float hn = dns.x + dns.y + bhn_s;
        sr = xor32_sum(sr);
        sz = xor32_sum(sz);
        hn = xor32_sum(hn);

        // gates; weights pre-scaled so exp2 needs no input multiply
        float r = fast_rcp(1.0f + fast_exp2(-sr));     // sigma: inf-safe (rcp(inf)=0)
        float z = fast_rcp(1.0f + fast_exp2(-sz));
        float ap = fmaf(r, hn, gn);                    // = 2*L2E*(gn_true + r*hn_true)
        ap = fmaxf(ap, -30.0f);                        // tanh ~ -1 beyond; avoids exp2 overflow
        float u  = fast_exp2(-ap);
        float nn = (1.0f - u) * fast_rcp(1.0f + u);    // tanh
        h = fmaf(z, h - nn, nn);                       // (1-z)*n + z*h
        hbuf[ss * HID + j] = h;                        // dup write, same value
    };

    // ---- q-head for 8 timesteps at once, from the h history ring ----
    auto qbatch = [&](int t0) {
        const float* hq = &hbuf[tq * HID + kq * 16];
        f4v QA = *reinterpret_cast<const f4v*>(hq + 0);
        f4v QB = *reinterpret_cast<const f4v*>(hq + 4);
        f4v QC = *reinterpret_cast<const f4v*>(hq + 8);
        f4v QD = *reinterpret_cast<const f4v*>(hq + 12);
        f4v qa = QA * wq4[0];
        qa += QB * wq4[1];
        qa += QC * wq4[2];
        qa += QD * wq4[3];
        float qp = (qa.x + qa.y) + (qa.z + qa.w);
        qp += SWZ_XOR(qp, 4);            // combine K-halves (lanes l^4)
        qp += bqv;
        float s = qp * qp;
        s += SWZ_XOR(s, 1);
        s += SWZ_XOR(s, 2);              // sum of 4 squared components
        float qv = qp * fast_rsq(s);
        if (!(lane & 4))                 // kq==0 lanes: 32 coalesced floats
            outp[(size_t)(t0 + tq) * 4 + m] = qv;
    };

    // ---- x double-buffer: 8-step windows (24 floats = 6 f4v, 16B aligned,
    //      wave-uniform addresses -> scalarizable loads) ----
    f4v xaA[6], xmA[6], xaB[6], xmB[6];
#pragma unroll
    for (int w = 0; w < 6; ++w) {
        xaA[w] = *reinterpret_cast<const f4v*>(accp + 4 * w);
        xmA[w] = *reinterpret_cast<const f4v*>(magp + 4 * w);
    }

#define WINDOW(XA, XM, XA_N, XM_N, T0)                                         \
    {                                                                          \
        const int tn = ((T0) + 8 < TLEN) ? ((T0) + 8) * 3 : 0;                 \
        _Pragma("unroll")                                                      \
        for (int w = 0; w < 6; ++w) {                                          \
            XA_N[w] = *reinterpret_cast<const f4v*>(accp + tn + 4 * w);        \
            XM_N[w] = *reinterpret_cast<const f4v*>(magp + tn + 4 * w);        \
        }                                                                      \
        _Pragma("unroll")                                                      \
        for (int s = 0; s < 8; ++s) {                                          \
            step((s + 7) & 7, s,                                               \
                 ELT(XA, 3 * s + 0), ELT(XA, 3 * s + 1), ELT(XA, 3 * s + 2),   \
                 ELT(XM, 3 * s + 0), ELT(XM, 3 * s + 1), ELT(XM, 3 * s + 2));  \
        }                                                                      \
        qbatch(T0);                                                            \
    }

    for (int t0 = 0; t0 < TLEN; t0 += 16) {
        WINDOW(xaA, xmA, xaB, xmB, t0);
        WINDOW(xaB, xmB, xaA, xmA, t0 + 8);
    }
#undef WINDOW
}

extern "C" void kernel_launch(void* const* d_in, const int* in_sizes, int n_in,
                              void* d_out, int out_size, void* d_ws, size_t ws_size,
                              hipStream_t stream) {
    const float* acc  = (const float*)d_in[0];
    const float* mag  = (const float*)d_in[1];
    const float* W_ih = (const float*)d_in[2];
    const float* W_hh = (const float*)d_in[3];
    const float* b_ih = (const float*)d_in[4];
    const float* b_hh = (const float*)d_in[5];
    const float* Wq   = (const float*)d_in[6];
    const float* bq   = (const float*)d_in[7];

    gru_fused_kernel<<<dim3(BATCH), dim3(64), 0, stream>>>(
        acc, mag, W_ih, W_hh, b_ih, b_hh, Wq, bq, (float*)d_out);
}

// Round 9
// 582.405 us; speedup vs baseline: 1.0329x; 1.0329x over previous
//
#include <hip/hip_runtime.h>
#include <hip/hip_bf16.h>

typedef float f2  __attribute__((ext_vector_type(2)));
typedef float f4v __attribute__((ext_vector_type(4)));

#ifndef __has_builtin
#define __has_builtin(x) 0
#endif

#define HID   32
#define TLEN  2048
#define BATCH 512
#define L2E   1.4426950408889634f   /* log2(e) */

__device__ __forceinline__ float fast_rcp(float x) {
#if __has_builtin(__builtin_amdgcn_rcpf)
    return __builtin_amdgcn_rcpf(x);
#else
    return 1.0f / x;
#endif
}
__device__ __forceinline__ float fast_rsq(float x) {
#if __has_builtin(__builtin_amdgcn_rsqf)
    return __builtin_amdgcn_rsqf(x);
#else
    return rsqrtf(x);
#endif
}
__device__ __forceinline__ float fast_exp2(float x) {
#if __has_builtin(__builtin_amdgcn_exp2f)
    return __builtin_amdgcn_exp2f(x);
#else
    return exp2f(x);
#endif
}

// sum of x over lane pairs (l, l^32) WITHOUT touching the DS pipe.
// v_permlane32_swap_b32 exchanges lanes0-31 of D with lanes32-63 of S;
// with both inputs = x, newD + newS == x[lane] + x[lane^32] in every lane.
__device__ __forceinline__ float xor32_sum(float x) {
#if __has_builtin(__builtin_amdgcn_permlane32_swap)
    typedef unsigned int u2v __attribute__((ext_vector_type(2)));
    u2v r = __builtin_amdgcn_permlane32_swap(__float_as_uint(x), __float_as_uint(x),
                                             false, false);
    return __uint_as_float(r.x) + __uint_as_float(r.y);
#else
    float a = x, b = x;
    asm("v_permlane32_swap_b32 %0, %1" : "+&v"(a), "+&v"(b));
    return a + b;
#endif
}

// ds_swizzle xor within 32-lane groups (BitMode: offset=(xor<<10)|(or<<5)|and)
#if __has_builtin(__builtin_amdgcn_ds_swizzle)
#define SWZ_XOR(x, XORM) \
    __int_as_float(__builtin_amdgcn_ds_swizzle(__float_as_int(x), ((XORM) << 10) | 0x1F))
#else
#define SWZ_XOR(x, XORM) __shfl_xor((x), (XORM))
#endif

// compile-time-index extraction from an f4v array (keeps values in registers)
#define ELT(arr, i) ((i) % 4 == 0 ? (arr)[(i)/4].x : \
                     (i) % 4 == 1 ? (arr)[(i)/4].y : \
                     (i) % 4 == 2 ? (arr)[(i)/4].z : (arr)[(i)/4].w)

// One wave per block, one batch element per wave.
// Gates: lane l -> output j = l&31, K-half = l>>5 (16-wide partial dot);
//        halves combined with permlane32_swap (VALU, no DS latency on chain).
// q-head: batched every 8 steps from an 8-slot h history ring in LDS:
//        lane l -> timestep tq = l>>3, K-half kq = (l>>2)&1, output m = l&3.
// All weights pre-scaled by log2e (r,z) / 2*log2e (n) so sigmoid/tanh use
// raw v_exp_f32 (=exp2) with no input multiply.
//
// __launch_bounds__(64, 1): min-waves-per-EU=1 -> register allocator may use
// the full VGPR budget.  Without it (round 3) the allocator targeted default
// occupancy (VGPR_Count=60) and REMATERIALIZED all weight loads inside the
// step loop -> ~668 cy/step of L1/L2 latency on the recurrence chain.
__global__ __launch_bounds__(64, 1) void gru_fused_kernel(
    const float* __restrict__ acc_g, const float* __restrict__ mag_g,
    const float* __restrict__ W_ih, const float* __restrict__ W_hh,
    const float* __restrict__ b_ih, const float* __restrict__ b_hh,
    const float* __restrict__ Wq, const float* __restrict__ bq,
    float* __restrict__ out)
{
    const int lane = threadIdx.x;
    const int j    = lane & 31;
    const int half = lane >> 5;
    const int kb   = half * 16;
    const int b    = blockIdx.x;

    const int tq = lane >> 3;        // q-head: timestep within 8-window
    const int kq = (lane >> 2) & 1;  // q-head: K-half
    const int m  = lane & 3;         // q-head: output component

    __shared__ float hbuf[8 * HID];  // h history ring, slot s = h after step (t0+s)

    // Opaque VGPR zero: added to the x base pointers so the compiler CANNOT
    // scalarize the (wave-uniform) window loads to s_load.  SMEM shares
    // lgkmcnt with DS and completes out-of-order, so scalarized x prefetches
    // force lgkmcnt(0) drains inside the recurrence; as global_load they sit
    // under vmcnt, fully decoupled from the per-step LDS waits.
    int vzero;
    asm("v_mov_b32 %0, 0" : "=v"(vzero));

    // ---- per-lane weight preload (registers), with exp2 pre-scaling ----
    f2 wr[8], wz[8], wn[8];
#pragma unroll
    for (int p = 0; p < 8; ++p) {
        wr[p] = L2E          * *reinterpret_cast<const f2*>(W_hh + (0 * HID + j) * HID + kb + 2 * p);
        wz[p] = L2E          * *reinterpret_cast<const f2*>(W_hh + (1 * HID + j) * HID + kb + 2 * p);
        wn[p] = (2.0f * L2E) * *reinterpret_cast<const f2*>(W_hh + (2 * HID + j) * HID + kb + 2 * p);
    }
    f4v wq4[4];
#pragma unroll
    for (int i = 0; i < 4; ++i)
        wq4[i] = *reinterpret_cast<const f4v*>(Wq + m * HID + kq * 16 + 4 * i);

    // gi weights: r/z HALVED (both K-halves accumulate (W/2)x pre-combine, the
    // permlane sum restores W*x); n-gate gi stays full (added post-combine,
    // since r multiplies only the hh part).
    float wir[6], wiz[6], win[6];
#pragma unroll
    for (int i = 0; i < 6; ++i) {
        wir[i] = 0.5f * L2E * W_ih[(0 * HID + j) * 6 + i];
        wiz[i] = 0.5f * L2E * W_ih[(1 * HID + j) * 6 + i];
        win[i] = 2.0f * L2E * W_ih[(2 * HID + j) * 6 + i];
    }
    const float br_s  = 0.5f * L2E * (b_ih[0 * HID + j] + b_hh[0 * HID + j]); // halved, pre-combine
    const float bz_s  = 0.5f * L2E * (b_ih[1 * HID + j] + b_hh[1 * HID + j]);
    const float bhn_s = L2E * b_hh[2 * HID + j];          // = 0.5 * 2L * bhn, pre-combine
    const float bin_s = 2.0f * L2E * b_ih[2 * HID + j];   // full, post-combine
    const float bqv   = bq[m];

    hbuf[7 * HID + j] = 0.0f;        // h_{-1} = 0 (slot 7; dup write from halves is benign)

    const float* accp = acc_g + (size_t)b * TLEN * 3 + vzero;
    const float* magp = mag_g + (size_t)b * TLEN * 3 + vzero;
    float* outp = out + (size_t)b * TLEN * 4;

    float h = 0.0f;                  // this lane's h_j

    // ---- one GRU step: read h_{t-1} from slot sp, write h_t to slot ss ----
    auto step = [&](int sp, int ss, float a0, float a1, float a2,
                                    float m0, float m1, float m2) {
        const float* hb = &hbuf[sp * HID + kb];
        f4v A = *reinterpret_cast<const f4v*>(hb + 0);   // broadcast ds_read_b128 x4
        f4v B = *reinterpret_cast<const f4v*>(hb + 4);
        f4v C = *reinterpret_cast<const f4v*>(hb + 8);
        f4v D = *reinterpret_cast<const f4v*>(hb + 12);
        f2 hp[8] = { {A.x,A.y},{A.z,A.w},{B.x,B.y},{B.z,B.w},
                     {C.x,C.y},{C.z,C.w},{D.x,D.y},{D.z,D.w} };

        // 16-wide partial dots, 2 accumulators per gate (4-deep chains)
        f2 dr0 = wr[0] * hp[0]; f2 dr1 = wr[4] * hp[4];
        f2 dz0 = wz[0] * hp[0]; f2 dz1 = wz[4] * hp[4];
        f2 dn0 = wn[0] * hp[0]; f2 dn1 = wn[4] * hp[4];
#pragma unroll
        for (int p = 1; p < 4; ++p) {
            dr0 += wr[p] * hp[p];  dr1 += wr[p + 4] * hp[p + 4];
            dz0 += wz[p] * hp[p];  dz1 += wz[p + 4] * hp[p + 4];
            dn0 += wn[p] * hp[p];  dn1 += wn[p + 4] * hp[p + 4];
        }

        // input-gate chains (independent of h -> fills LDS-read latency)
        float gr = fmaf(a2, wir[2], fmaf(a1, wir[1], fmaf(a0, wir[0], br_s)));
        gr = fmaf(m2, wir[5], fmaf(m1, wir[4], fmaf(m0, wir[3], gr)));
        float gz = fmaf(a2, wiz[2], fmaf(a1, wiz[1], fmaf(a0, wiz[0], bz_s)));
        gz = fmaf(m2, wiz[5], fmaf(m1, wiz[4], fmaf(m0, wiz[3], gz)));
        float gn = fmaf(a2, win[2], fmaf(a1, win[1], fmaf(a0, win[0], bin_s)));
        gn = fmaf(m2, win[5], fmaf(m1, win[4], fmaf(m0, win[3], gn)));

        // horizontal + cross-half combine (permlane32_swap: VALU, not DS)
        f2 drs = dr0 + dr1; float sr = drs.x + drs.y + gr;
        f2 dzs = dz0 + dz1; float sz = dzs.x + dzs.y + gz;
        f2 dns = dn0 + dn1; float hn = dns.x + dns.y + bhn_s;
        sr = xor32_sum(sr);
        sz = xor32_sum(sz);
        hn = xor32_sum(hn);

        // gates; weights pre-scaled so exp2 needs no input multiply
        float r = fast_rcp(1.0f + fast_exp2(-sr));     // sigma: inf-safe (rcp(inf)=0)
        float z = fast_rcp(1.0f + fast_exp2(-sz));
        float ap = fmaf(r, hn, gn);                    // = 2*L2E*(gn_true + r*hn_true)
        ap = fmaxf(ap, -30.0f);                        // tanh ~ -1 beyond; avoids exp2 overflow
        float u  = fast_exp2(-ap);
        float nn = (1.0f - u) * fast_rcp(1.0f + u);    // tanh
        h = fmaf(z, h - nn, nn);                       // (1-z)*n + z*h
        hbuf[ss * HID + j] = h;                        // dup write, same value
    };

    // ---- q-head for 8 timesteps at once, from the h history ring ----
    auto qbatch = [&](int t0) {
        const float* hq = &hbuf[tq * HID + kq * 16];
        f4v QA = *reinterpret_cast<const f4v*>(hq + 0);
        f4v QB = *reinterpret_cast<const f4v*>(hq + 4);
        f4v QC = *reinterpret_cast<const f4v*>(hq + 8);
        f4v QD = *reinterpret_cast<const f4v*>(hq + 12);
        f4v qa = QA * wq4[0];
        qa += QB * wq4[1];
        qa += QC * wq4[2];
        qa += QD * wq4[3];
        float qp = (qa.x + qa.y) + (qa.z + qa.w);
        qp += SWZ_XOR(qp, 4);            // combine K-halves (lanes l^4)
        qp += bqv;
        float s = qp * qp;
        s += SWZ_XOR(s, 1);
        s += SWZ_XOR(s, 2);              // sum of 4 squared components
        float qv = qp * fast_rsq(s);
        if (!(lane & 4))                 // kq==0 lanes: 32 coalesced floats
            outp[(size_t)(t0 + tq) * 4 + m] = qv;
    };

    // ---- x double-buffer: 8-step windows (24 floats = 6 f4v, 16B aligned,
    //      VGPR addresses -> global_load under vmcnt, off the lgkm chain) ----
    f4v xaA[6], xmA[6], xaB[6], xmB[6];
#pragma unroll
    for (int w = 0; w < 6; ++w) {
        xaA[w] = *reinterpret_cast<const f4v*>(accp + 4 * w);
        xmA[w] = *reinterpret_cast<const f4v*>(magp + 4 * w);
    }

#define WINDOW(XA, XM, XA_N, XM_N, T0)                                         \
    {                                                                          \
        const int tn = ((T0) + 8 < TLEN) ? ((T0) + 8) * 3 : 0;                 \
        _Pragma("unroll")                                                      \
        for (int w = 0; w < 6; ++w) {                                          \
            XA_N[w] = *reinterpret_cast<const f4v*>(accp + tn + 4 * w);        \
            XM_N[w] = *reinterpret_cast<const f4v*>(magp + tn + 4 * w);        \
        }                                                                      \
        _Pragma("unroll")                                                      \
        for (int s = 0; s < 8; ++s) {                                          \
            step((s + 7) & 7, s,                                               \
                 ELT(XA, 3 * s + 0), ELT(XA, 3 * s + 1), ELT(XA, 3 * s + 2),   \
                 ELT(XM, 3 * s + 0), ELT(XM, 3 * s + 1), ELT(XM, 3 * s + 2));  \
        }                                                                      \
        qbatch(T0);                                                            \
    }

    for (int t0 = 0; t0 < TLEN; t0 += 16) {
        WINDOW(xaA, xmA, xaB, xmB, t0);
        WINDOW(xaB, xmB, xaA, xmA, t0 + 8);
    }
#undef WINDOW
}

extern "C" void kernel_launch(void* const* d_in, const int* in_sizes, int n_in,
                              void* d_out, int out_size, void* d_ws, size_t ws_size,
                              hipStream_t stream) {
    const float* acc  = (const float*)d_in[0];
    const float* mag  = (const float*)d_in[1];
    const float* W_ih = (const float*)d_in[2];
    const float* W_hh = (const float*)d_in[3];
    const float* b_ih = (const float*)d_in[4];
    const float* b_hh = (const float*)d_in[5];
    const float* Wq   = (const float*)d_in[6];
    const float* bq   = (const float*)d_in[7];

    gru_fused_kernel<<<dim3(BATCH), dim3(64), 0, stream>>>(
        acc, mag, W_ih, W_hh, b_ih, b_hh, Wq, bq, (float*)d_out);
}